// Round 2
// baseline (1166.815 us; speedup 1.0000x reference)
//
#include <hip/hip_runtime.h>
#include <stdint.h>

// ---- problem dims (BailingMoE: T=1024 H=2048 E=16 I=1408 S=2 topk=4) ----
// All tensors FLOAT32. MFMA is bf16 with fp32 accumulate. Routed experts
// computed SPARSELY (top-4 only) via per-expert gather lists.
// v3: native (__bf16) casts -> compiler emits v_cvt_pk_bf16_f32 (round-1 was
//     VALU-bound on hand-rolled RNE bit-twiddle: VALUBusy 28% vs MfmaUtil 13%).
//     x pre-converted to bf16 once in router (A staging = pure uint4 copy).
//     actR compacted via per-expert prefix bases (ws 49.6 -> 27.4 MiB).
//     Grid reordered y-fastest so weight-sharing blocks are dispatch-adjacent.
#define T_TOK 1024
#define H_DIM 2048
#define E_NUM 16
#define I_DIM 1408
#define IS_DIM 2816   // I*S (shared intermediate half-width)
#define TOPK 4

#define BK 32
#define LDP 40        // LDS row pitch in bf16 elems (80 B, 16B-aligned rows)

typedef unsigned short u16;
typedef __bf16 bf16x8 __attribute__((ext_vector_type(8)));
typedef __bf16 bf16x4v __attribute__((ext_vector_type(4)));
typedef float f32x4 __attribute__((ext_vector_type(4)));

__device__ __forceinline__ u16 f2bf(float f) {
  __bf16 h = (__bf16)f;              // compiler: v_cvt_pk_bf16_f32 (RNE)
  u16 r; __builtin_memcpy(&r, &h, 2); return r;
}

__device__ __forceinline__ uint2 cvt4(float4 v) {
  bf16x4v h;
  h[0] = (__bf16)v.x; h[1] = (__bf16)v.y;
  h[2] = (__bf16)v.z; h[3] = (__bf16)v.w;
  uint2 o; __builtin_memcpy(&o, &h, 8); return o;
}

__device__ __forceinline__ f32x4 mfma16(bf16x8 a, bf16x8 b, f32x4 c) {
  return __builtin_amdgcn_mfma_f32_16x16x32_bf16(a, b, c, 0, 0, 0);
}

// ============================ router (+ x -> bf16 copy) ============================
__global__ __launch_bounds__(256) void router_kernel(
    const float* __restrict__ x, const float* __restrict__ gw,
    float* __restrict__ combine, int* __restrict__ topk_idx,
    u16* __restrict__ xb) {
  __shared__ float partial[256];
  __shared__ float logits[E_NUM];
  const int t = blockIdx.x, tid = threadIdx.x;
  const int e = tid >> 4, l16 = tid & 15;
  const float* xr = x + (size_t)t * H_DIM;
  const float* wr = gw + (size_t)e * H_DIM;
  float s = 0.f;
  for (int h = l16 * 4; h < H_DIM; h += 64) {
    float4 xv = *(const float4*)&xr[h];
    float4 wv = *(const float4*)&wr[h];
    s += xv.x * wv.x + xv.y * wv.y + xv.z * wv.z + xv.w * wv.w;
  }
  partial[tid] = s;
  // bf16 copy of this token's row (8 elems/thread, exactly covers H_DIM)
  {
    const int h0 = tid * 8;
    float4 v0 = *(const float4*)&xr[h0];
    float4 v1 = *(const float4*)&xr[h0 + 4];
    uint2 a = cvt4(v0), b = cvt4(v1);
    uint4 o; o.x = a.x; o.y = a.y; o.z = b.x; o.w = b.y;
    *(uint4*)&xb[(size_t)t * H_DIM + h0] = o;
  }
  __syncthreads();
  if (tid < E_NUM) {
    float tot = 0.f;
    for (int j = 0; j < 16; ++j) tot += partial[tid * 16 + j];
    logits[tid] = tot;
  }
  __syncthreads();
  if (tid == 0) {
    float p[E_NUM];
    float mx = -1e30f;
    for (int i = 0; i < E_NUM; ++i) mx = fmaxf(mx, logits[i]);
    float sum = 0.f;
    for (int i = 0; i < E_NUM; ++i) { p[i] = expf(logits[i] - mx); sum += p[i]; }
    float inv = 1.f / sum;
    for (int i = 0; i < E_NUM; ++i) p[i] *= inv;
    bool used[E_NUM];
    for (int i = 0; i < E_NUM; ++i) used[i] = false;
    int idx[TOPK]; float w4[TOPK]; float wsum = 0.f;
    for (int k = 0; k < TOPK; ++k) {
      int best = 0; float bv = -1.f;
      for (int i = 0; i < E_NUM; ++i)
        if (!used[i] && p[i] > bv) { bv = p[i]; best = i; }
      used[best] = true; idx[k] = best; w4[k] = bv; wsum += bv;
    }
    float outw[E_NUM];
    for (int i = 0; i < E_NUM; ++i) outw[i] = 0.f;
    float winv = 1.f / wsum;
    for (int k = 0; k < TOPK; ++k) {
      outw[idx[k]] = w4[k] * winv;
      topk_idx[t * TOPK + k] = idx[k];
    }
    for (int i = 0; i < E_NUM; ++i) combine[(size_t)t * E_NUM + i] = outw[i];
  }
}

// =================== per-expert gather-list build (+ prefix bases) ==========
__global__ __launch_bounds__(256) void assign_kernel(
    const int* __restrict__ topk_idx, int* __restrict__ list,
    int* __restrict__ cnt, int* __restrict__ cntPad, int* __restrict__ base) {
  __shared__ int lcnt[E_NUM], lcur[E_NUM], lpad[E_NUM];
  const int tid = threadIdx.x;
  if (tid < E_NUM) { lcnt[tid] = 0; lcur[tid] = 0; }
  __syncthreads();
  for (int t = tid; t < T_TOK; t += 256)
    for (int k = 0; k < TOPK; ++k)
      atomicAdd(&lcnt[topk_idx[t * TOPK + k]], 1);
  __syncthreads();
  for (int t = tid; t < T_TOK; t += 256)
    for (int k = 0; k < TOPK; ++k) {
      int e = topk_idx[t * TOPK + k];
      int p = atomicAdd(&lcur[e], 1);
      list[e * T_TOK + p] = t;
    }
  __syncthreads();
  if (tid < E_NUM) {
    int c = lcnt[tid];
    int cp = (c + 127) / 128 * 128;
    cnt[tid] = c;
    cntPad[tid] = cp;
    lpad[tid] = cp;
    int last = (c > 0) ? list[tid * T_TOK + c - 1] : 0;
    for (int p = c; p < cp; ++p) list[tid * T_TOK + p] = last;
  }
  __syncthreads();
  if (tid == 0) {
    int b = 0;
    for (int e2 = 0; e2 < E_NUM; ++e2) { base[e2] = b; b += lpad[e2]; }
  }
}

// =================== fused gate_up + SiLU*mul (routed z<16, shared z>=16) ===
// Tile 128(M) x 64(N), BK=32, 4 waves (2x2, each 64x32). acc = 64 AGPR.
// A is bf16 (pre-converted) -> staging is pure uint4 copy; weights fp32
// converted via cvt_pk during staging. Reg-prefetch of next K-tile.
__global__ __launch_bounds__(256, 2) void gateup_kernel(
    const u16* __restrict__ Xb, const float* __restrict__ Wgu,
    const float* __restrict__ Wsh, const float* __restrict__ combine,
    const int* __restrict__ list, const int* __restrict__ cntPad,
    const int* __restrict__ base, u16* __restrict__ actR,
    u16* __restrict__ actS) {
  __shared__ u16 As[128 * LDP];
  __shared__ u16 Wg[64 * LDP];
  __shared__ u16 Wu[64 * LDP];
  __shared__ int ltok[128];
  const int z = blockIdx.z;
  const int row0 = blockIdx.x * 128;   // y-tile is fastest-varying now
  const int tid = threadIdx.x;
  const int srow = tid >> 3, scol = (tid & 7) * 4;    // weight staging (fp32)
  const int srowA = tid >> 2, scolA = (tid & 3) * 8;  // A staging (bf16)

  const u16 *Aq0, *Aq1;
  const float *Wgp, *Wup;
  int n0;
  size_t outRow0 = 0;
  if (z >= E_NUM) {            // ---- shared expert path ----
    n0 = (blockIdx.y + (z - E_NUM) * 22) * 64;   // 44 n-tiles over IS_DIM
    Wgp = Wsh + (size_t)(n0 + srow) * H_DIM + scol;
    Wup = Wsh + (size_t)(IS_DIM + n0 + srow) * H_DIM + scol;
    Aq0 = Xb + (size_t)(row0 + srowA) * H_DIM + scolA;
    Aq1 = Xb + (size_t)(row0 + 64 + srowA) * H_DIM + scolA;
  } else {                     // ---- routed expert z ----
    if (row0 >= cntPad[z]) return;
    if (tid < 128) ltok[tid] = list[z * T_TOK + row0 + tid];
    __syncthreads();
    n0 = blockIdx.y * 64;
    Wgp = Wgu + (size_t)z * (2 * I_DIM * H_DIM) + (size_t)(n0 + srow) * H_DIM + scol;
    Wup = Wgp + (size_t)I_DIM * H_DIM;
    Aq0 = Xb + (size_t)ltok[srowA] * H_DIM + scolA;
    Aq1 = Xb + (size_t)ltok[64 + srowA] * H_DIM + scolA;
    outRow0 = (size_t)(base[z] + row0);
  }

  const int wave = tid >> 6, lane = tid & 63;
  const int lane16 = lane & 15, quad = lane >> 4;
  const int wm = wave >> 1, wn = wave & 1;

  const f32x4 zero = {0.f, 0.f, 0.f, 0.f};
  f32x4 accg[4][2], accu[4][2];
#pragma unroll
  for (int i = 0; i < 4; ++i)
#pragma unroll
    for (int j = 0; j < 2; ++j) { accg[i][j] = zero; accu[i][j] = zero; }

  uint4 pa0, pa1; float4 pg0, pg1, pu0, pu1;
#define GU_LOAD(k0)                                 \
  pa0 = *(const uint4*)(Aq0 + (k0));                \
  pa1 = *(const uint4*)(Aq1 + (k0));                \
  pg0 = *(const float4*)(Wgp + (k0));               \
  pg1 = *(const float4*)(Wgp + 32 * H_DIM + (k0));  \
  pu0 = *(const float4*)(Wup + (k0));               \
  pu1 = *(const float4*)(Wup + 32 * H_DIM + (k0));

  GU_LOAD(0)
  for (int k0 = 0; k0 < H_DIM; k0 += BK) {
    *(uint4*)&As[srowA * LDP + scolA]        = pa0;
    *(uint4*)&As[(64 + srowA) * LDP + scolA] = pa1;
    *(uint2*)&Wg[srow * LDP + scol]          = cvt4(pg0);
    *(uint2*)&Wg[(32 + srow) * LDP + scol]   = cvt4(pg1);
    *(uint2*)&Wu[srow * LDP + scol]          = cvt4(pu0);
    *(uint2*)&Wu[(32 + srow) * LDP + scol]   = cvt4(pu1);
    __syncthreads();
    if (k0 + BK < H_DIM) { GU_LOAD(k0 + BK) }   // overlap with ds_read+MFMA
    bf16x8 a[4], bg[2], bu[2];
#pragma unroll
    for (int i = 0; i < 4; ++i)
      a[i] = *(const bf16x8*)&As[(wm * 64 + i * 16 + lane16) * LDP + quad * 8];
#pragma unroll
    for (int j = 0; j < 2; ++j) {
      bg[j] = *(const bf16x8*)&Wg[(wn * 32 + j * 16 + lane16) * LDP + quad * 8];
      bu[j] = *(const bf16x8*)&Wu[(wn * 32 + j * 16 + lane16) * LDP + quad * 8];
    }
#pragma unroll
    for (int i = 0; i < 4; ++i)
#pragma unroll
      for (int j = 0; j < 2; ++j) {
        accg[i][j] = mfma16(a[i], bg[j], accg[i][j]);
        accu[i][j] = mfma16(a[i], bu[j], accu[i][j]);
      }
    __syncthreads();
  }
#undef GU_LOAD

  if (z >= E_NUM) {
#pragma unroll
    for (int i = 0; i < 4; ++i)
#pragma unroll
      for (int j = 0; j < 2; ++j) {
        const int col = n0 + wn * 32 + j * 16 + lane16;
#pragma unroll
        for (int r = 0; r < 4; ++r) {
          const int row = row0 + wm * 64 + i * 16 + quad * 4 + r;
          float g = accg[i][j][r], u = accu[i][j][r];
          actS[(size_t)row * IS_DIM + col] = f2bf(g / (1.f + __expf(-g)) * u);
        }
      }
  } else {
#pragma unroll
    for (int i = 0; i < 4; ++i)
#pragma unroll
      for (int j = 0; j < 2; ++j) {
        const int col = n0 + wn * 32 + j * 16 + lane16;
#pragma unroll
        for (int r = 0; r < 4; ++r) {
          const int rl = wm * 64 + i * 16 + quad * 4 + r;
          float g = accg[i][j][r], u = accu[i][j][r];
          float act = g / (1.f + __expf(-g)) * u;
          act *= combine[(size_t)ltok[rl] * E_NUM + z];
          actR[(outRow0 + rl) * I_DIM + col] = f2bf(act);
        }
      }
  }
}

// =================== fused down-proj (routed z<16, shared z=16) =============
// Tile 128x128, BK=32, 4 waves (2x2, each 64x64). acc = 64 AGPR.
// out is pre-zeroed; BOTH paths atomicAdd (they race within one launch).
__global__ __launch_bounds__(256, 2) void down_kernel(
    const u16* __restrict__ actR, const u16* __restrict__ actS,
    const float* __restrict__ Wd, const float* __restrict__ Wsd,
    const int* __restrict__ list, const int* __restrict__ cnt,
    const int* __restrict__ cntPad, const int* __restrict__ base,
    float* __restrict__ out) {
  __shared__ u16 As[128 * LDP];
  __shared__ u16 Bs[128 * LDP];
  __shared__ int ltok[128];
  const int z = blockIdx.z;
  const int row0 = blockIdx.x * 128;   // y-tile fastest
  const int col0 = blockIdx.y * 128;
  const int tid = threadIdx.x;
  const int arow = tid >> 2, acol = (tid & 3) * 8;   // A: bf16 128x32
  const int brow = tid >> 3, bcol = (tid & 7) * 4;   // B: fp32 128x32

  int K, c = 0;
  const u16* Ap;
  const float* Bp;
  if (z == E_NUM) {            // ---- shared down ----
    K = IS_DIM;
    Ap = actS + (size_t)(row0 + arow) * IS_DIM + acol;
    Bp = Wsd + (size_t)(col0 + brow) * IS_DIM + bcol;
  } else {                     // ---- routed down ----
    if (row0 >= cntPad[z]) return;
    if (tid < 128) ltok[tid] = list[z * T_TOK + row0 + tid];
    c = cnt[z];
    K = I_DIM;
    Ap = actR + ((size_t)base[z] + row0 + arow) * I_DIM + acol;
    Bp = Wd + ((size_t)z * H_DIM + col0 + brow) * I_DIM + bcol;
  }
  const u16* Ap1 = Ap + (size_t)64 * K;
  const float* Bp1 = Bp + (size_t)32 * K;
  const float* Bp2 = Bp + (size_t)64 * K;
  const float* Bp3 = Bp + (size_t)96 * K;

  const int wave = tid >> 6, lane = tid & 63;
  const int lane16 = lane & 15, quad = lane >> 4;
  const int wm = wave >> 1, wn = wave & 1;

  const f32x4 zero = {0.f, 0.f, 0.f, 0.f};
  f32x4 acc[4][4];
#pragma unroll
  for (int i = 0; i < 4; ++i)
#pragma unroll
    for (int j = 0; j < 4; ++j) acc[i][j] = zero;

  uint4 qa0, qa1; float4 pb0, pb1, pb2, pb3;
#define DN_LOAD(k0)                        \
  qa0 = *(const uint4*)(Ap + (k0));        \
  qa1 = *(const uint4*)(Ap1 + (k0));       \
  pb0 = *(const float4*)(Bp + (k0));       \
  pb1 = *(const float4*)(Bp1 + (k0));      \
  pb2 = *(const float4*)(Bp2 + (k0));      \
  pb3 = *(const float4*)(Bp3 + (k0));

  DN_LOAD(0)
  for (int k0 = 0; k0 < K; k0 += BK) {
    *(uint4*)&As[arow * LDP + acol]        = qa0;
    *(uint4*)&As[(64 + arow) * LDP + acol] = qa1;
    *(uint2*)&Bs[brow * LDP + bcol]        = cvt4(pb0);
    *(uint2*)&Bs[(32 + brow) * LDP + bcol] = cvt4(pb1);
    *(uint2*)&Bs[(64 + brow) * LDP + bcol] = cvt4(pb2);
    *(uint2*)&Bs[(96 + brow) * LDP + bcol] = cvt4(pb3);
    __syncthreads();
    if (k0 + BK < K) { DN_LOAD(k0 + BK) }
    bf16x8 a[4], b[4];
#pragma unroll
    for (int i = 0; i < 4; ++i)
      a[i] = *(const bf16x8*)&As[(wm * 64 + i * 16 + lane16) * LDP + quad * 8];
#pragma unroll
    for (int j = 0; j < 4; ++j)
      b[j] = *(const bf16x8*)&Bs[(wn * 64 + j * 16 + lane16) * LDP + quad * 8];
#pragma unroll
    for (int i = 0; i < 4; ++i)
#pragma unroll
      for (int j = 0; j < 4; ++j) acc[i][j] = mfma16(a[i], b[j], acc[i][j]);
    __syncthreads();
  }
#undef DN_LOAD

  if (z == E_NUM) {
#pragma unroll
    for (int i = 0; i < 4; ++i)
#pragma unroll
      for (int j = 0; j < 4; ++j) {
        const int col = col0 + wn * 64 + j * 16 + lane16;
#pragma unroll
        for (int r = 0; r < 4; ++r) {
          const int row = row0 + wm * 64 + i * 16 + quad * 4 + r;
          atomicAdd(&out[(size_t)row * H_DIM + col], acc[i][j][r]);
        }
      }
  } else {
#pragma unroll
    for (int i = 0; i < 4; ++i)
#pragma unroll
      for (int j = 0; j < 4; ++j) {
        const int col = col0 + wn * 64 + j * 16 + lane16;
#pragma unroll
        for (int r = 0; r < 4; ++r) {
          const int rl = wm * 64 + i * 16 + quad * 4 + r;
          if (row0 + rl < c)
            atomicAdd(&out[(size_t)ltok[rl] * H_DIM + col], acc[i][j][r]);
        }
      }
  }
}

// ============================ launch ============================
extern "C" void kernel_launch(void* const* d_in, const int* in_sizes, int n_in,
                              void* d_out, int out_size, void* d_ws,
                              size_t ws_size, hipStream_t stream) {
  const float* x = (const float*)d_in[0];           // [1024,2048]
  const float* gate_w = (const float*)d_in[1];      // [16,2048]
  const float* w_gate_up = (const float*)d_in[2];   // [16,2816,2048]
  const float* w_down = (const float*)d_in[3];      // [16,2048,1408]
  const float* shared_gu = (const float*)d_in[4];   // [5632,2048]
  const float* shared_down = (const float*)d_in[5]; // [2048,2816]
  float* out = (float*)d_out;

  char* ws = (char*)d_ws;
  float* combine = (float*)ws;                 // 64 KiB fp32 [T,E]
  int* topk_idx = (int*)(ws + 65536);          // 16 KiB [T,4]
  int* list = (int*)(ws + 81920);              // 64 KiB [E,1024]
  int* cnt = (int*)(ws + 147456);              // 64 B
  int* cntPad = (int*)(ws + 147520);           // 64 B
  int* base = (int*)(ws + 147584);             // 64 B
  u16* xb = (u16*)(ws + 147648);               // 4 MiB bf16 [T,H]
  u16* actS = (u16*)(ws + 147648 + 4194304);   // 5.77 MB bf16 [T,2816]
  u16* actR = (u16*)(ws + 147648 + 4194304 + 5767168);  // 17.3 MB bf16 [6144,1408]
  // total ws usage: ~27.4 MiB (was 49.6 MiB)

  router_kernel<<<T_TOK, 256, 0, stream>>>(x, gate_w, combine, topk_idx, xb);
  assign_kernel<<<1, 256, 0, stream>>>(topk_idx, list, cnt, cntPad, base);
  hipMemsetAsync(out, 0, (size_t)T_TOK * H_DIM * sizeof(float), stream);

  // z = 0..15 routed experts, z = 16..17 shared expert (44 n-tiles = 2 x 22)
  gateup_kernel<<<dim3(8, 22, 18), 256, 0, stream>>>(
      xb, w_gate_up, shared_gu, combine, list, cntPad, base, actR, actS);

  // z = 0..15 routed down (scatter atomics), z = 16 shared down (atomics)
  down_kernel<<<dim3(8, 16, 17), 256, 0, stream>>>(
      actR, actS, w_down, shared_down, list, cnt, cntPad, base, out);
}

// Round 3
// 881.720 us; speedup vs baseline: 1.3233x; 1.3233x over previous
//
#include <hip/hip_runtime.h>
#include <stdint.h>

// ---- problem dims (BailingMoE: T=1024 H=2048 E=16 I=1408 S=2 topk=4) ----
// All tensors FLOAT32. MFMA is bf16 with fp32 accumulate. Routed experts
// computed SPARSELY (top-4 only) via per-expert gather lists.
// v4: REVERT round-2 grid-axis order. Lesson: workgroup->XCD is round-robin
//     by dispatch index (mod 8). With row-tile as fastest axis (8 slots) and
//     cntPad~256, surviving routed blocks sat at positions {0,1} mod 8 ->
//     all routed work on XCDs 0-1 (occupancy 26.7->11.9%, dur 266->446us).
//     n/col-tile must be the fastest axis so early-exits form contiguous runs.
//     KEEP v3 wins: native cvt_pk bf16 conversion (VALUBusy 28->5.4%),
//     x pre-converted to bf16 (pure uint4 A-staging), compacted actR.
//     NEW: __launch_bounds__(256,3) -> 3 blocks/CU (68 VGPR + 64 AGPR = 132
//     <= 170; LDS 21KB*3 = 63KB) for better latency hiding.
#define T_TOK 1024
#define H_DIM 2048
#define E_NUM 16
#define I_DIM 1408
#define IS_DIM 2816   // I*S (shared intermediate half-width)
#define TOPK 4

#define BK 32
#define LDP 40        // LDS row pitch in bf16 elems (80 B): stride 20 banks ->
                      // perfect 2-way (free, m136) on ds_read_b128

typedef unsigned short u16;
typedef __bf16 bf16x8 __attribute__((ext_vector_type(8)));
typedef __bf16 bf16x4v __attribute__((ext_vector_type(4)));
typedef float f32x4 __attribute__((ext_vector_type(4)));

__device__ __forceinline__ u16 f2bf(float f) {
  __bf16 h = (__bf16)f;              // compiler: v_cvt_pk_bf16_f32 (RNE)
  u16 r; __builtin_memcpy(&r, &h, 2); return r;
}

__device__ __forceinline__ uint2 cvt4(float4 v) {
  bf16x4v h;
  h[0] = (__bf16)v.x; h[1] = (__bf16)v.y;
  h[2] = (__bf16)v.z; h[3] = (__bf16)v.w;
  uint2 o; __builtin_memcpy(&o, &h, 8); return o;
}

__device__ __forceinline__ f32x4 mfma16(bf16x8 a, bf16x8 b, f32x4 c) {
  return __builtin_amdgcn_mfma_f32_16x16x32_bf16(a, b, c, 0, 0, 0);
}

// ============================ router (+ x -> bf16 copy) ======================
__global__ __launch_bounds__(256) void router_kernel(
    const float* __restrict__ x, const float* __restrict__ gw,
    float* __restrict__ combine, int* __restrict__ topk_idx,
    u16* __restrict__ xb) {
  __shared__ float partial[256];
  __shared__ float logits[E_NUM];
  const int t = blockIdx.x, tid = threadIdx.x;
  const int e = tid >> 4, l16 = tid & 15;
  const float* xr = x + (size_t)t * H_DIM;
  const float* wr = gw + (size_t)e * H_DIM;
  float s = 0.f;
  for (int h = l16 * 4; h < H_DIM; h += 64) {
    float4 xv = *(const float4*)&xr[h];
    float4 wv = *(const float4*)&wr[h];
    s += xv.x * wv.x + xv.y * wv.y + xv.z * wv.z + xv.w * wv.w;
  }
  partial[tid] = s;
  // bf16 copy of this token's row (8 elems/thread, exactly covers H_DIM)
  {
    const int h0 = tid * 8;
    float4 v0 = *(const float4*)&xr[h0];
    float4 v1 = *(const float4*)&xr[h0 + 4];
    uint2 a = cvt4(v0), b = cvt4(v1);
    uint4 o; o.x = a.x; o.y = a.y; o.z = b.x; o.w = b.y;
    *(uint4*)&xb[(size_t)t * H_DIM + h0] = o;
  }
  __syncthreads();
  if (tid < E_NUM) {
    float tot = 0.f;
    for (int j = 0; j < 16; ++j) tot += partial[tid * 16 + j];
    logits[tid] = tot;
  }
  __syncthreads();
  if (tid == 0) {
    float p[E_NUM];
    float mx = -1e30f;
    for (int i = 0; i < E_NUM; ++i) mx = fmaxf(mx, logits[i]);
    float sum = 0.f;
    for (int i = 0; i < E_NUM; ++i) { p[i] = expf(logits[i] - mx); sum += p[i]; }
    float inv = 1.f / sum;
    for (int i = 0; i < E_NUM; ++i) p[i] *= inv;
    bool used[E_NUM];
    for (int i = 0; i < E_NUM; ++i) used[i] = false;
    int idx[TOPK]; float w4[TOPK]; float wsum = 0.f;
    for (int k = 0; k < TOPK; ++k) {
      int best = 0; float bv = -1.f;
      for (int i = 0; i < E_NUM; ++i)
        if (!used[i] && p[i] > bv) { bv = p[i]; best = i; }
      used[best] = true; idx[k] = best; w4[k] = bv; wsum += bv;
    }
    float outw[E_NUM];
    for (int i = 0; i < E_NUM; ++i) outw[i] = 0.f;
    float winv = 1.f / wsum;
    for (int k = 0; k < TOPK; ++k) {
      outw[idx[k]] = w4[k] * winv;
      topk_idx[t * TOPK + k] = idx[k];
    }
    for (int i = 0; i < E_NUM; ++i) combine[(size_t)t * E_NUM + i] = outw[i];
  }
}

// =================== per-expert gather-list build (+ prefix bases) ==========
__global__ __launch_bounds__(256) void assign_kernel(
    const int* __restrict__ topk_idx, int* __restrict__ list,
    int* __restrict__ cnt, int* __restrict__ cntPad, int* __restrict__ base) {
  __shared__ int lcnt[E_NUM], lcur[E_NUM], lpad[E_NUM];
  const int tid = threadIdx.x;
  if (tid < E_NUM) { lcnt[tid] = 0; lcur[tid] = 0; }
  __syncthreads();
  for (int t = tid; t < T_TOK; t += 256)
    for (int k = 0; k < TOPK; ++k)
      atomicAdd(&lcnt[topk_idx[t * TOPK + k]], 1);
  __syncthreads();
  for (int t = tid; t < T_TOK; t += 256)
    for (int k = 0; k < TOPK; ++k) {
      int e = topk_idx[t * TOPK + k];
      int p = atomicAdd(&lcur[e], 1);
      list[e * T_TOK + p] = t;
    }
  __syncthreads();
  if (tid < E_NUM) {
    int c = lcnt[tid];
    int cp = (c + 127) / 128 * 128;
    cnt[tid] = c;
    cntPad[tid] = cp;
    lpad[tid] = cp;
    int last = (c > 0) ? list[tid * T_TOK + c - 1] : 0;
    for (int p = c; p < cp; ++p) list[tid * T_TOK + p] = last;
  }
  __syncthreads();
  if (tid == 0) {
    int b = 0;
    for (int e2 = 0; e2 < E_NUM; ++e2) { base[e2] = b; b += lpad[e2]; }
  }
}

// =================== fused gate_up + SiLU*mul (routed z<16, shared z>=16) ===
// Tile 128(M) x 64(N), BK=32, 4 waves (2x2, each 64x32). acc = 64 AGPR.
// blockIdx.x = n-tile (FASTEST: spreads work across XCDs; early-exit blocks
// form contiguous runs of 22). blockIdx.y = row-tile. Reg-prefetch next K.
__global__ __launch_bounds__(256, 3) void gateup_kernel(
    const u16* __restrict__ Xb, const float* __restrict__ Wgu,
    const float* __restrict__ Wsh, const float* __restrict__ combine,
    const int* __restrict__ list, const int* __restrict__ cntPad,
    const int* __restrict__ base, u16* __restrict__ actR,
    u16* __restrict__ actS) {
  __shared__ u16 As[128 * LDP];
  __shared__ u16 Wg[64 * LDP];
  __shared__ u16 Wu[64 * LDP];
  __shared__ int ltok[128];
  const int z = blockIdx.z;
  const int row0 = blockIdx.y * 128;
  const int tid = threadIdx.x;
  const int srow = tid >> 3, scol = (tid & 7) * 4;    // weight staging (fp32)
  const int srowA = tid >> 2, scolA = (tid & 3) * 8;  // A staging (bf16)

  const u16 *Aq0, *Aq1;
  const float *Wgp, *Wup;
  int n0;
  size_t outRow0 = 0;
  if (z >= E_NUM) {            // ---- shared expert path ----
    n0 = (blockIdx.x + (z - E_NUM) * 22) * 64;   // 44 n-tiles over IS_DIM
    Wgp = Wsh + (size_t)(n0 + srow) * H_DIM + scol;
    Wup = Wsh + (size_t)(IS_DIM + n0 + srow) * H_DIM + scol;
    Aq0 = Xb + (size_t)(row0 + srowA) * H_DIM + scolA;
    Aq1 = Xb + (size_t)(row0 + 64 + srowA) * H_DIM + scolA;
  } else {                     // ---- routed expert z ----
    if (row0 >= cntPad[z]) return;
    if (tid < 128) ltok[tid] = list[z * T_TOK + row0 + tid];
    __syncthreads();
    n0 = blockIdx.x * 64;
    Wgp = Wgu + (size_t)z * (2 * I_DIM * H_DIM) + (size_t)(n0 + srow) * H_DIM + scol;
    Wup = Wgp + (size_t)I_DIM * H_DIM;
    Aq0 = Xb + (size_t)ltok[srowA] * H_DIM + scolA;
    Aq1 = Xb + (size_t)ltok[64 + srowA] * H_DIM + scolA;
    outRow0 = (size_t)(base[z] + row0);
  }

  const int wave = tid >> 6, lane = tid & 63;
  const int lane16 = lane & 15, quad = lane >> 4;
  const int wm = wave >> 1, wn = wave & 1;

  const f32x4 zero = {0.f, 0.f, 0.f, 0.f};
  f32x4 accg[4][2], accu[4][2];
#pragma unroll
  for (int i = 0; i < 4; ++i)
#pragma unroll
    for (int j = 0; j < 2; ++j) { accg[i][j] = zero; accu[i][j] = zero; }

  uint4 pa0, pa1; float4 pg0, pg1, pu0, pu1;
#define GU_LOAD(k0)                                 \
  pa0 = *(const uint4*)(Aq0 + (k0));                \
  pa1 = *(const uint4*)(Aq1 + (k0));                \
  pg0 = *(const float4*)(Wgp + (k0));               \
  pg1 = *(const float4*)(Wgp + 32 * H_DIM + (k0));  \
  pu0 = *(const float4*)(Wup + (k0));               \
  pu1 = *(const float4*)(Wup + 32 * H_DIM + (k0));

  GU_LOAD(0)
  for (int k0 = 0; k0 < H_DIM; k0 += BK) {
    *(uint4*)&As[srowA * LDP + scolA]        = pa0;
    *(uint4*)&As[(64 + srowA) * LDP + scolA] = pa1;
    *(uint2*)&Wg[srow * LDP + scol]          = cvt4(pg0);
    *(uint2*)&Wg[(32 + srow) * LDP + scol]   = cvt4(pg1);
    *(uint2*)&Wu[srow * LDP + scol]          = cvt4(pu0);
    *(uint2*)&Wu[(32 + srow) * LDP + scol]   = cvt4(pu1);
    __syncthreads();
    if (k0 + BK < H_DIM) { GU_LOAD(k0 + BK) }   // overlap with ds_read+MFMA
    bf16x8 a[4], bg[2], bu[2];
#pragma unroll
    for (int i = 0; i < 4; ++i)
      a[i] = *(const bf16x8*)&As[(wm * 64 + i * 16 + lane16) * LDP + quad * 8];
#pragma unroll
    for (int j = 0; j < 2; ++j) {
      bg[j] = *(const bf16x8*)&Wg[(wn * 32 + j * 16 + lane16) * LDP + quad * 8];
      bu[j] = *(const bf16x8*)&Wu[(wn * 32 + j * 16 + lane16) * LDP + quad * 8];
    }
#pragma unroll
    for (int i = 0; i < 4; ++i)
#pragma unroll
      for (int j = 0; j < 2; ++j) {
        accg[i][j] = mfma16(a[i], bg[j], accg[i][j]);
        accu[i][j] = mfma16(a[i], bu[j], accu[i][j]);
      }
    __syncthreads();
  }
#undef GU_LOAD

  if (z >= E_NUM) {
#pragma unroll
    for (int i = 0; i < 4; ++i)
#pragma unroll
      for (int j = 0; j < 2; ++j) {
        const int col = n0 + wn * 32 + j * 16 + lane16;
#pragma unroll
        for (int r = 0; r < 4; ++r) {
          const int row = row0 + wm * 64 + i * 16 + quad * 4 + r;
          float g = accg[i][j][r], u = accu[i][j][r];
          actS[(size_t)row * IS_DIM + col] = f2bf(g / (1.f + __expf(-g)) * u);
        }
      }
  } else {
#pragma unroll
    for (int i = 0; i < 4; ++i)
#pragma unroll
      for (int j = 0; j < 2; ++j) {
        const int col = n0 + wn * 32 + j * 16 + lane16;
#pragma unroll
        for (int r = 0; r < 4; ++r) {
          const int rl = wm * 64 + i * 16 + quad * 4 + r;
          float g = accg[i][j][r], u = accu[i][j][r];
          float act = g / (1.f + __expf(-g)) * u;
          act *= combine[(size_t)ltok[rl] * E_NUM + z];
          actR[(outRow0 + rl) * I_DIM + col] = f2bf(act);
        }
      }
  }
}

// =================== fused down-proj (routed z<16, shared z=16) =============
// Tile 128x128, BK=32, 4 waves (2x2, each 64x64). acc = 64 AGPR.
// blockIdx.x = col-tile (FASTEST, 16-wide: XCD spread). out pre-zeroed;
// BOTH paths atomicAdd (they race within one launch).
__global__ __launch_bounds__(256, 3) void down_kernel(
    const u16* __restrict__ actR, const u16* __restrict__ actS,
    const float* __restrict__ Wd, const float* __restrict__ Wsd,
    const int* __restrict__ list, const int* __restrict__ cnt,
    const int* __restrict__ cntPad, const int* __restrict__ base,
    float* __restrict__ out) {
  __shared__ u16 As[128 * LDP];
  __shared__ u16 Bs[128 * LDP];
  __shared__ int ltok[128];
  const int z = blockIdx.z;
  const int row0 = blockIdx.y * 128;
  const int col0 = blockIdx.x * 128;
  const int tid = threadIdx.x;
  const int arow = tid >> 2, acol = (tid & 3) * 8;   // A: bf16 128x32
  const int brow = tid >> 3, bcol = (tid & 7) * 4;   // B: fp32 128x32

  int K, c = 0;
  const u16* Ap;
  const float* Bp;
  if (z == E_NUM) {            // ---- shared down ----
    K = IS_DIM;
    Ap = actS + (size_t)(row0 + arow) * IS_DIM + acol;
    Bp = Wsd + (size_t)(col0 + brow) * IS_DIM + bcol;
  } else {                     // ---- routed down ----
    if (row0 >= cntPad[z]) return;
    if (tid < 128) ltok[tid] = list[z * T_TOK + row0 + tid];
    c = cnt[z];
    K = I_DIM;
    Ap = actR + ((size_t)base[z] + row0 + arow) * I_DIM + acol;
    Bp = Wd + ((size_t)z * H_DIM + col0 + brow) * I_DIM + bcol;
  }
  const u16* Ap1 = Ap + (size_t)64 * K;
  const float* Bp1 = Bp + (size_t)32 * K;
  const float* Bp2 = Bp + (size_t)64 * K;
  const float* Bp3 = Bp + (size_t)96 * K;

  const int wave = tid >> 6, lane = tid & 63;
  const int lane16 = lane & 15, quad = lane >> 4;
  const int wm = wave >> 1, wn = wave & 1;

  const f32x4 zero = {0.f, 0.f, 0.f, 0.f};
  f32x4 acc[4][4];
#pragma unroll
  for (int i = 0; i < 4; ++i)
#pragma unroll
    for (int j = 0; j < 4; ++j) acc[i][j] = zero;

  uint4 qa0, qa1; float4 pb0, pb1, pb2, pb3;
#define DN_LOAD(k0)                        \
  qa0 = *(const uint4*)(Ap + (k0));        \
  qa1 = *(const uint4*)(Ap1 + (k0));       \
  pb0 = *(const float4*)(Bp + (k0));       \
  pb1 = *(const float4*)(Bp1 + (k0));      \
  pb2 = *(const float4*)(Bp2 + (k0));      \
  pb3 = *(const float4*)(Bp3 + (k0));

  DN_LOAD(0)
  for (int k0 = 0; k0 < K; k0 += BK) {
    *(uint4*)&As[arow * LDP + acol]        = qa0;
    *(uint4*)&As[(64 + arow) * LDP + acol] = qa1;
    *(uint2*)&Bs[brow * LDP + bcol]        = cvt4(pb0);
    *(uint2*)&Bs[(32 + brow) * LDP + bcol] = cvt4(pb1);
    *(uint2*)&Bs[(64 + brow) * LDP + bcol] = cvt4(pb2);
    *(uint2*)&Bs[(96 + brow) * LDP + bcol] = cvt4(pb3);
    __syncthreads();
    if (k0 + BK < K) { DN_LOAD(k0 + BK) }
    bf16x8 a[4], b[4];
#pragma unroll
    for (int i = 0; i < 4; ++i)
      a[i] = *(const bf16x8*)&As[(wm * 64 + i * 16 + lane16) * LDP + quad * 8];
#pragma unroll
    for (int j = 0; j < 4; ++j)
      b[j] = *(const bf16x8*)&Bs[(wn * 64 + j * 16 + lane16) * LDP + quad * 8];
#pragma unroll
    for (int i = 0; i < 4; ++i)
#pragma unroll
      for (int j = 0; j < 4; ++j) acc[i][j] = mfma16(a[i], b[j], acc[i][j]);
    __syncthreads();
  }
#undef DN_LOAD

  if (z == E_NUM) {
#pragma unroll
    for (int i = 0; i < 4; ++i)
#pragma unroll
      for (int j = 0; j < 4; ++j) {
        const int col = col0 + wn * 64 + j * 16 + lane16;
#pragma unroll
        for (int r = 0; r < 4; ++r) {
          const int row = row0 + wm * 64 + i * 16 + quad * 4 + r;
          atomicAdd(&out[(size_t)row * H_DIM + col], acc[i][j][r]);
        }
      }
  } else {
#pragma unroll
    for (int i = 0; i < 4; ++i)
#pragma unroll
      for (int j = 0; j < 4; ++j) {
        const int col = col0 + wn * 64 + j * 16 + lane16;
#pragma unroll
        for (int r = 0; r < 4; ++r) {
          const int rl = wm * 64 + i * 16 + quad * 4 + r;
          if (row0 + rl < c)
            atomicAdd(&out[(size_t)ltok[rl] * H_DIM + col], acc[i][j][r]);
        }
      }
  }
}

// ============================ launch ============================
extern "C" void kernel_launch(void* const* d_in, const int* in_sizes, int n_in,
                              void* d_out, int out_size, void* d_ws,
                              size_t ws_size, hipStream_t stream) {
  const float* x = (const float*)d_in[0];           // [1024,2048]
  const float* gate_w = (const float*)d_in[1];      // [16,2048]
  const float* w_gate_up = (const float*)d_in[2];   // [16,2816,2048]
  const float* w_down = (const float*)d_in[3];      // [16,2048,1408]
  const float* shared_gu = (const float*)d_in[4];   // [5632,2048]
  const float* shared_down = (const float*)d_in[5]; // [2048,2816]
  float* out = (float*)d_out;

  char* ws = (char*)d_ws;
  float* combine = (float*)ws;                 // 64 KiB fp32 [T,E]
  int* topk_idx = (int*)(ws + 65536);          // 16 KiB [T,4]
  int* list = (int*)(ws + 81920);              // 64 KiB [E,1024]
  int* cnt = (int*)(ws + 147456);              // 64 B
  int* cntPad = (int*)(ws + 147520);           // 64 B
  int* base = (int*)(ws + 147584);             // 64 B
  u16* xb = (u16*)(ws + 147648);               // 4 MiB bf16 [T,H]
  u16* actS = (u16*)(ws + 147648 + 4194304);   // 5.77 MB bf16 [T,2816]
  u16* actR = (u16*)(ws + 147648 + 4194304 + 5767168);  // 17.3 MB bf16 [6144,1408]
  // total ws usage: ~27.4 MiB

  router_kernel<<<T_TOK, 256, 0, stream>>>(x, gate_w, combine, topk_idx, xb);
  assign_kernel<<<1, 256, 0, stream>>>(topk_idx, list, cnt, cntPad, base);
  hipMemsetAsync(out, 0, (size_t)T_TOK * H_DIM * sizeof(float), stream);

  // x = n-tile (fastest; XCD spread), y = row-tile, z = expert (16 routed + 2 shared)
  gateup_kernel<<<dim3(22, 8, 18), 256, 0, stream>>>(
      xb, w_gate_up, shared_gu, combine, list, cntPad, base, actR, actS);

  // x = col-tile (fastest), y = row-tile, z = expert (16 routed + 1 shared)
  down_kernel<<<dim3(16, 8, 17), 256, 0, stream>>>(
      actR, actS, w_down, shared_down, list, cnt, cntPad, base, out);
}